// Round 1
// baseline (1042.610 us; speedup 1.0000x reference)
//
#include <hip/hip_runtime.h>
#include <hip/hip_bf16.h>

// Problem constants (from reference)
#define N_NODES 50000
#define N_EDGES 640000
#define F_IN 64
#define EDGE_DIM 16
#define HID 128
#define N_LAYERS 3
#define NUM_GRAPHS 64
#define BN_EPS 1e-5f

// ---------------------------------------------------------------------------
// CSR build: histogram -> block reduce -> scan of block sums -> block scan ->
// bucket fill. row_ptr doubles as the degree array during the histogram.
// ---------------------------------------------------------------------------
__global__ void k_hist(const int* __restrict__ dst, int* __restrict__ deg) {
    int e = blockIdx.x * 256 + threadIdx.x;   // grid exact: 2500*256 = 640000
    atomicAdd(&deg[dst[e]], 1);
}

__global__ void k_blockred(const int* __restrict__ deg, int* __restrict__ bsums) {
    __shared__ int s[256];
    int i = blockIdx.x * 256 + threadIdx.x;
    int v = (i < N_NODES) ? deg[i] : 0;
    s[threadIdx.x] = v;
    __syncthreads();
    for (int off = 128; off > 0; off >>= 1) {
        if (threadIdx.x < off) s[threadIdx.x] += s[threadIdx.x + off];
        __syncthreads();
    }
    if (threadIdx.x == 0) bsums[blockIdx.x] = s[0];
}

__global__ void k_scan_bsums(int* __restrict__ bsums, int nb) {
    if (threadIdx.x == 0) {
        int run = 0;
        for (int i = 0; i < nb; ++i) { int v = bsums[i]; bsums[i] = run; run += v; }
    }
}

__global__ void k_scan_blocks(int* __restrict__ deg_rowptr, const int* __restrict__ bsums,
                              int* __restrict__ cursor) {
    __shared__ int s[256];
    int tid = threadIdx.x;
    int i = blockIdx.x * 256 + tid;
    int v = (i < N_NODES) ? deg_rowptr[i] : 0;
    s[tid] = v;
    __syncthreads();
    // Hillis-Steele inclusive scan
    for (int off = 1; off < 256; off <<= 1) {
        int t = 0;
        if (tid >= off) t = s[tid - off];
        __syncthreads();
        s[tid] += t;
        __syncthreads();
    }
    int excl = s[tid] - v + bsums[blockIdx.x];
    if (i < N_NODES) {
        deg_rowptr[i] = excl;
        cursor[i] = excl;
    }
    if (i == N_NODES - 1) deg_rowptr[N_NODES] = N_EDGES;
}

__global__ void k_fill(const int* __restrict__ dst, int* __restrict__ cursor,
                       int* __restrict__ elist) {
    int e = blockIdx.x * 256 + threadIdx.x;   // exact
    int p = atomicAdd(&cursor[dst[e]], 1);
    elist[p] = e;
}

// ---------------------------------------------------------------------------
// Shared GEMM micro-kernel: 64x128 block tile, 256 threads, thread = (tr,tc),
// TM=4 rows strided 16, TN=8 cols as two float4 groups (tc*4 and 64+tc*4).
// Processes one K-chunk of 32 from As (LDA) and Bs (ld 132).
// ---------------------------------------------------------------------------
template <int LDA>
__device__ __forceinline__ void micro32(const float* __restrict__ As,
                                        const float* __restrict__ Bs,
                                        int tr, int tc4, int koff,
                                        float acc[4][8]) {
#pragma unroll
    for (int k4 = 0; k4 < 32; k4 += 4) {
        float4 a4[4];
#pragma unroll
        for (int i = 0; i < 4; ++i)
            a4[i] = *(const float4*)&As[(tr + 16 * i) * LDA + koff + k4];
#pragma unroll
        for (int kk = 0; kk < 4; ++kk) {
            const float4 b0v = *(const float4*)&Bs[(k4 + kk) * 132 + tc4];
            const float4 b1v = *(const float4*)&Bs[(k4 + kk) * 132 + 64 + tc4];
#pragma unroll
            for (int i = 0; i < 4; ++i) {
                const float av = ((const float*)&a4[i])[kk];
                acc[i][0] = fmaf(av, b0v.x, acc[i][0]);
                acc[i][1] = fmaf(av, b0v.y, acc[i][1]);
                acc[i][2] = fmaf(av, b0v.z, acc[i][2]);
                acc[i][3] = fmaf(av, b0v.w, acc[i][3]);
                acc[i][4] = fmaf(av, b1v.x, acc[i][4]);
                acc[i][5] = fmaf(av, b1v.y, acc[i][5]);
                acc[i][6] = fmaf(av, b1v.z, acc[i][6]);
                acc[i][7] = fmaf(av, b1v.w, acc[i][7]);
            }
        }
    }
}

// ---------------------------------------------------------------------------
// Encoder: h = x @ enc_W + enc_b   (M=50000, K=64, N=128)
// ---------------------------------------------------------------------------
__global__ __launch_bounds__(256) void k_enc(const float* __restrict__ x,
                                             const float* __restrict__ W,
                                             const float* __restrict__ b,
                                             float* __restrict__ h) {
    __shared__ float As[64 * 68];
    __shared__ float Bs[32 * 132];
    const int tid = threadIdx.x;
    const int row0 = blockIdx.x * 64;
    // stage A tile 64x64
#pragma unroll
    for (int i = 0; i < 4; ++i) {
        int idx = i * 1024 + tid * 4;
        int r = idx >> 6, c = idx & 63;
        float4 v = make_float4(0.f, 0.f, 0.f, 0.f);
        if (row0 + r < N_NODES) v = *(const float4*)&x[(row0 + r) * F_IN + c];
        *(float4*)&As[r * 68 + c] = v;
    }
    float acc[4][8];
#pragma unroll
    for (int i = 0; i < 4; ++i)
#pragma unroll
        for (int j = 0; j < 8; ++j) acc[i][j] = 0.f;

    const int tr = tid >> 4, tc4 = (tid & 15) * 4;
    for (int kc = 0; kc < 2; ++kc) {
        __syncthreads();
#pragma unroll
        for (int i = 0; i < 4; ++i) {
            int idx = i * 1024 + tid * 4;
            int r = idx >> 7, c = idx & 127;
            *(float4*)&Bs[r * 132 + c] = *(const float4*)&W[(kc * 32 + r) * HID + c];
        }
        __syncthreads();
        micro32<68>(As, Bs, tr, tc4, kc * 32, acc);
    }
    const float4 bb0 = *(const float4*)&b[tc4];
    const float4 bb1 = *(const float4*)&b[64 + tc4];
#pragma unroll
    for (int i = 0; i < 4; ++i) {
        int r = row0 + tr + 16 * i;
        if (r < N_NODES) {
            float4 o0 = make_float4(acc[i][0] + bb0.x, acc[i][1] + bb0.y,
                                    acc[i][2] + bb0.z, acc[i][3] + bb0.w);
            float4 o1 = make_float4(acc[i][4] + bb1.x, acc[i][5] + bb1.y,
                                    acc[i][6] + bb1.z, acc[i][7] + bb1.w);
            *(float4*)&h[r * HID + tc4] = o0;
            *(float4*)&h[r * HID + 64 + tc4] = o1;
        }
    }
}

// ---------------------------------------------------------------------------
// GINE aggregation (gather-style, no float atomics):
// z[n] = h[n] + sum_{e: dst(e)=n} relu(h[src(e)] + edge_attr[e] @ We + be)
// 32 lanes per node (4 feats each as float4); We kept in 64 VGPRs per lane.
// ---------------------------------------------------------------------------
#define EFMA(AV, J)                                   \
    ef.x = fmaf((AV), w[J].x, ef.x);                  \
    ef.y = fmaf((AV), w[J].y, ef.y);                  \
    ef.z = fmaf((AV), w[J].z, ef.z);                  \
    ef.w = fmaf((AV), w[J].w, ef.w);

__global__ __launch_bounds__(256) void k_agg(const float* __restrict__ h,
                                             const int* __restrict__ esrc,
                                             const float* __restrict__ eattr,
                                             const float* __restrict__ We,
                                             const float* __restrict__ be,
                                             const int* __restrict__ row_ptr,
                                             const int* __restrict__ elist,
                                             float* __restrict__ z) {
    const int tid = threadIdx.x;
    const int f4 = (tid & 31) * 4;
    const int grp = tid >> 5;             // 8 nodes per block
    float4 w[16];
#pragma unroll
    for (int j = 0; j < 16; ++j) w[j] = *(const float4*)&We[j * HID + f4];
    const float4 eb = *(const float4*)&be[f4];

    const int n = blockIdx.x * 8 + grp;   // grid exact: 6250*8 = 50000
    const int base = row_ptr[n];
    const int end = row_ptr[n + 1];
    float4 acc = *(const float4*)&h[n * HID + f4];

    for (int p = base; p < end; ++p) {
        const int eid = elist[p];
        const int src = esrc[eid];
        const float4 a0 = *(const float4*)&eattr[eid * EDGE_DIM];
        const float4 a1 = *(const float4*)&eattr[eid * EDGE_DIM + 4];
        const float4 a2 = *(const float4*)&eattr[eid * EDGE_DIM + 8];
        const float4 a3 = *(const float4*)&eattr[eid * EDGE_DIM + 12];
        float4 ef = eb;
        EFMA(a0.x, 0)  EFMA(a0.y, 1)  EFMA(a0.z, 2)  EFMA(a0.w, 3)
        EFMA(a1.x, 4)  EFMA(a1.y, 5)  EFMA(a1.z, 6)  EFMA(a1.w, 7)
        EFMA(a2.x, 8)  EFMA(a2.y, 9)  EFMA(a2.z, 10) EFMA(a2.w, 11)
        EFMA(a3.x, 12) EFMA(a3.y, 13) EFMA(a3.z, 14) EFMA(a3.w, 15)
        const float4 hs = *(const float4*)&h[src * HID + f4];
        acc.x += fmaxf(hs.x + ef.x, 0.f);
        acc.y += fmaxf(hs.y + ef.y, 0.f);
        acc.z += fmaxf(hs.z + ef.z, 0.f);
        acc.w += fmaxf(hs.w + ef.w, 0.f);
    }
    *(float4*)&z[n * HID + f4] = acc;
}

// ---------------------------------------------------------------------------
// Fused node MLP: z2 = relu(z @ W1 + b1) @ W2 + b2, plus per-column
// sum / sumsq partials for BN (atomics into bn[0:128] / bn[128:256]).
// ---------------------------------------------------------------------------
__global__ __launch_bounds__(256) void k_mlp(const float* __restrict__ z,
                                             const float* __restrict__ W1,
                                             const float* __restrict__ b1,
                                             const float* __restrict__ W2,
                                             const float* __restrict__ b2,
                                             float* __restrict__ z2,
                                             float* __restrict__ bn) {
    __shared__ float As[64 * 132];
    __shared__ float Bs[32 * 132];
    __shared__ float red[16 * 128];
    const int tid = threadIdx.x;
    const int row0 = blockIdx.x * 64;
    // stage z tile 64x128
#pragma unroll
    for (int i = 0; i < 8; ++i) {
        int idx = i * 1024 + tid * 4;
        int r = idx >> 7, c = idx & 127;
        float4 v = make_float4(0.f, 0.f, 0.f, 0.f);
        if (row0 + r < N_NODES) v = *(const float4*)&z[(row0 + r) * HID + c];
        *(float4*)&As[r * 132 + c] = v;
    }
    const int tr = tid >> 4, tc4 = (tid & 15) * 4;
    float acc[4][8];
#pragma unroll
    for (int i = 0; i < 4; ++i)
#pragma unroll
        for (int j = 0; j < 8; ++j) acc[i][j] = 0.f;

    // GEMM 1: z @ W1
    for (int kc = 0; kc < 4; ++kc) {
        __syncthreads();
#pragma unroll
        for (int i = 0; i < 4; ++i) {
            int idx = i * 1024 + tid * 4;
            int r = idx >> 7, c = idx & 127;
            *(float4*)&Bs[r * 132 + c] = *(const float4*)&W1[(kc * 32 + r) * HID + c];
        }
        __syncthreads();
        micro32<132>(As, Bs, tr, tc4, kc * 32, acc);
    }
    // bias + relu, write z1 back to As
    {
        const float4 bb0 = *(const float4*)&b1[tc4];
        const float4 bb1 = *(const float4*)&b1[64 + tc4];
        __syncthreads();   // all GEMM1 reads of As done
#pragma unroll
        for (int i = 0; i < 4; ++i) {
            int rl = tr + 16 * i;
            float4 o0 = make_float4(fmaxf(acc[i][0] + bb0.x, 0.f), fmaxf(acc[i][1] + bb0.y, 0.f),
                                    fmaxf(acc[i][2] + bb0.z, 0.f), fmaxf(acc[i][3] + bb0.w, 0.f));
            float4 o1 = make_float4(fmaxf(acc[i][4] + bb1.x, 0.f), fmaxf(acc[i][5] + bb1.y, 0.f),
                                    fmaxf(acc[i][6] + bb1.z, 0.f), fmaxf(acc[i][7] + bb1.w, 0.f));
            *(float4*)&As[rl * 132 + tc4] = o0;
            *(float4*)&As[rl * 132 + 64 + tc4] = o1;
        }
#pragma unroll
        for (int i = 0; i < 4; ++i)
#pragma unroll
            for (int j = 0; j < 8; ++j) acc[i][j] = 0.f;
    }
    // GEMM 2: z1 @ W2
    for (int kc = 0; kc < 4; ++kc) {
        __syncthreads();
#pragma unroll
        for (int i = 0; i < 4; ++i) {
            int idx = i * 1024 + tid * 4;
            int r = idx >> 7, c = idx & 127;
            *(float4*)&Bs[r * 132 + c] = *(const float4*)&W2[(kc * 32 + r) * HID + c];
        }
        __syncthreads();
        micro32<132>(As, Bs, tr, tc4, kc * 32, acc);
    }
    // bias, store z2, BN partials
    const float4 bb0 = *(const float4*)&b2[tc4];
    const float4 bb1 = *(const float4*)&b2[64 + tc4];
    float outv[4][8];
    bool valid[4];
#pragma unroll
    for (int i = 0; i < 4; ++i) {
        valid[i] = (row0 + tr + 16 * i) < N_NODES;
        outv[i][0] = acc[i][0] + bb0.x; outv[i][1] = acc[i][1] + bb0.y;
        outv[i][2] = acc[i][2] + bb0.z; outv[i][3] = acc[i][3] + bb0.w;
        outv[i][4] = acc[i][4] + bb1.x; outv[i][5] = acc[i][5] + bb1.y;
        outv[i][6] = acc[i][6] + bb1.z; outv[i][7] = acc[i][7] + bb1.w;
        if (valid[i]) {
            int r = row0 + tr + 16 * i;
            *(float4*)&z2[r * HID + tc4] = make_float4(outv[i][0], outv[i][1], outv[i][2], outv[i][3]);
            *(float4*)&z2[r * HID + 64 + tc4] = make_float4(outv[i][4], outv[i][5], outv[i][6], outv[i][7]);
        }
    }
    float s[8], sq[8];
#pragma unroll
    for (int j = 0; j < 8; ++j) { s[j] = 0.f; sq[j] = 0.f; }
#pragma unroll
    for (int i = 0; i < 4; ++i) {
        if (valid[i]) {
#pragma unroll
            for (int j = 0; j < 8; ++j) {
                s[j] += outv[i][j];
                sq[j] = fmaf(outv[i][j], outv[i][j], sq[j]);
            }
        }
    }
    __syncthreads();
    *(float4*)&red[tr * 128 + tc4] = make_float4(s[0], s[1], s[2], s[3]);
    *(float4*)&red[tr * 128 + 64 + tc4] = make_float4(s[4], s[5], s[6], s[7]);
    __syncthreads();
    if (tid < 128) {
        float t = 0.f;
#pragma unroll
        for (int r = 0; r < 16; ++r) t += red[r * 128 + tid];
        atomicAdd(&bn[tid], t);
    }
    __syncthreads();
    *(float4*)&red[tr * 128 + tc4] = make_float4(sq[0], sq[1], sq[2], sq[3]);
    *(float4*)&red[tr * 128 + 64 + tc4] = make_float4(sq[4], sq[5], sq[6], sq[7]);
    __syncthreads();
    if (tid < 128) {
        float t = 0.f;
#pragma unroll
        for (int r = 0; r < 16; ++r) t += red[r * 128 + tid];
        atomicAdd(&bn[128 + tid], t);
    }
}

// ---------------------------------------------------------------------------
// BN (batch stats) + ReLU:  h = relu(gamma*(z2-mean)*rsqrt(var+eps)+beta)
// ---------------------------------------------------------------------------
__global__ __launch_bounds__(256) void k_bnrelu(const float* __restrict__ z2,
                                                const float* __restrict__ bn,
                                                const float* __restrict__ gamma,
                                                const float* __restrict__ beta,
                                                float* __restrict__ h) {
    const int idx = (blockIdx.x * 256 + threadIdx.x) * 4;   // exact: 6250*256*4 = 6.4M
    const int c = idx & 127;
    const float invN = 1.0f / (float)N_NODES;
    float4 v = *(const float4*)&z2[idx];
    float o[4] = {v.x, v.y, v.z, v.w};
#pragma unroll
    for (int k = 0; k < 4; ++k) {
        const float m = bn[c + k] * invN;
        float var = bn[128 + c + k] * invN - m * m;
        var = fmaxf(var, 0.f);
        const float r = rsqrtf(var + BN_EPS);
        o[k] = fmaxf(gamma[c + k] * (o[k] - m) * r + beta[c + k], 0.f);
    }
    *(float4*)&h[idx] = make_float4(o[0], o[1], o[2], o[3]);
}

// ---------------------------------------------------------------------------
// Global add pool (batch is sorted): register accumulate, flush on change.
// ---------------------------------------------------------------------------
__global__ void k_pool(const float* __restrict__ h, const int* __restrict__ batch,
                       float* __restrict__ g) {
    const int f = threadIdx.x;            // 128 threads
    const int n0 = blockIdx.x * 128;
    const int nend = min(n0 + 128, N_NODES);
    float acc = 0.f;
    int cur = batch[n0];
    for (int n = n0; n < nend; ++n) {
        const int bb = batch[n];
        if (bb != cur) {
            atomicAdd(&g[cur * HID + f], acc);
            acc = 0.f;
            cur = bb;
        }
        acc += h[n * HID + f];
    }
    atomicAdd(&g[cur * HID + f], acc);
}

// ---------------------------------------------------------------------------
// Head
// ---------------------------------------------------------------------------
__global__ void k_head1(const float* __restrict__ g, const float* __restrict__ W,
                        const float* __restrict__ b, float* __restrict__ g1) {
    const int idx = blockIdx.x * 256 + threadIdx.x;   // 32*256 = 8192
    const int r = idx >> 7, c = idx & 127;
    float acc = b[c];
    for (int k = 0; k < 128; ++k) acc = fmaf(g[r * HID + k], W[k * HID + c], acc);
    g1[idx] = fmaxf(acc, 0.f);
}

__global__ void k_head2(const float* __restrict__ g1, const float* __restrict__ W,
                        const float* __restrict__ b, float* __restrict__ out) {
    const int idx = threadIdx.x;          // 128
    const int r = idx >> 1, c = idx & 1;
    float acc = b[c];
    for (int k = 0; k < 128; ++k) acc = fmaf(g1[r * HID + k], W[k * 2 + c], acc);
    out[idx] = acc;
}

// ---------------------------------------------------------------------------
// Launch
// ---------------------------------------------------------------------------
extern "C" void kernel_launch(void* const* d_in, const int* in_sizes, int n_in,
                              void* d_out, int out_size, void* d_ws, size_t ws_size,
                              hipStream_t stream) {
    const float* x     = (const float*)d_in[0];
    const int*   ei    = (const int*)d_in[1];
    const float* eattr = (const float*)d_in[2];
    const int*   batch = (const int*)d_in[3];
    const float* encW  = (const float*)d_in[4];
    const float* encb  = (const float*)d_in[5];
    const float* eW    = (const float*)d_in[6];
    const float* eb    = (const float*)d_in[7];
    const float* W1    = (const float*)d_in[8];
    const float* b1    = (const float*)d_in[9];
    const float* W2    = (const float*)d_in[10];
    const float* b2    = (const float*)d_in[11];
    const float* gam   = (const float*)d_in[12];
    const float* bet   = (const float*)d_in[13];
    const float* hW1   = (const float*)d_in[14];
    const float* hb1   = (const float*)d_in[15];
    const float* hW2   = (const float*)d_in[16];
    const float* hb2   = (const float*)d_in[17];
    float* out = (float*)d_out;

    // workspace layout (floats); total ~80 MB
    float* ws = (float*)d_ws;
    float* h   = ws;                       // 6,400,000
    float* z   = ws + 6400000;             // 6,400,000
    float* z2  = ws + 12800000;            // 6,400,000
    float* bn  = ws + 19200000;            // 256
    float* g   = ws + 19200256;            // 8,192
    float* g1  = ws + 19208448;            // 8,192
    int* row_ptr = (int*)(ws + 19216640);  // 50,001
    int* cursor  = row_ptr + N_NODES + 1;  // 50,000
    int* elist   = cursor + N_NODES;       // 640,000
    int* bsums   = elist + N_EDGES;        // 256

    const int* esrc = ei;
    const int* edst = ei + N_EDGES;

    // CSR build (every call; edge_index is restored before each timed call)
    hipMemsetAsync(row_ptr, 0, (N_NODES + 1) * sizeof(int), stream);
    k_hist<<<N_EDGES / 256, 256, 0, stream>>>(edst, row_ptr);
    k_blockred<<<196, 256, 0, stream>>>(row_ptr, bsums);
    k_scan_bsums<<<1, 64, 0, stream>>>(bsums, 196);
    k_scan_blocks<<<196, 256, 0, stream>>>(row_ptr, bsums, cursor);
    k_fill<<<N_EDGES / 256, 256, 0, stream>>>(edst, cursor, elist);

    // encoder
    k_enc<<<782, 256, 0, stream>>>(x, encW, encb, h);

    for (int l = 0; l < N_LAYERS; ++l) {
        k_agg<<<6250, 256, 0, stream>>>(h, esrc, eattr, eW + l * EDGE_DIM * HID,
                                        eb + l * HID, row_ptr, elist, z);
        hipMemsetAsync(bn, 0, 256 * sizeof(float), stream);
        k_mlp<<<782, 256, 0, stream>>>(z, W1 + l * HID * HID, b1 + l * HID,
                                       W2 + l * HID * HID, b2 + l * HID, z2, bn);
        k_bnrelu<<<6250, 256, 0, stream>>>(z2, bn, gam + l * HID, bet + l * HID, h);
    }

    hipMemsetAsync(g, 0, NUM_GRAPHS * HID * sizeof(float), stream);
    k_pool<<<391, 128, 0, stream>>>(h, batch, g);
    k_head1<<<32, 256, 0, stream>>>(g, hW1, hb1, g1);
    k_head2<<<1, 128, 0, stream>>>(g1, hW2, hb2, out);
}